// Round 1
// baseline (239.570 us; speedup 1.0000x reference)
//
#include <hip/hip_runtime.h>
#include <math.h>

#define N_ENTITY 200000
#define N_REL 32
#define DIM 64
#define N_HOP 2
#define N_MEM 32
#define BATCH 1024

__device__ __forceinline__ float wave_reduce_sum(float v) {
    v += __shfl_xor(v, 1);
    v += __shfl_xor(v, 2);
    v += __shfl_xor(v, 4);
    v += __shfl_xor(v, 8);
    v += __shfl_xor(v, 16);
    v += __shfl_xor(v, 32);
    return v;
}

// One block per batch item b. 256 threads = 4 waves.
// Phase 1 (v-independent, fully parallel): for all 64 (hop,m) pairs compute
//   Rh[hop][m][:]  (stored to LDS), t (stored to LDS), hRt -> kge partial,
//   and l2 partials (h^2 + t^2 + R^2).
// Phase 2 (hop-sequential, cheap): attention probs from Rh.v, softmax over M,
//   o = t.probs, v = W(v+o); final score = sigmoid(v.y).
__global__ __launch_bounds__(256, 4) void ripple_main(
    const int* __restrict__ items,
    const float* __restrict__ labels,
    const int* __restrict__ mh,
    const int* __restrict__ mr,
    const int* __restrict__ mt,
    const float* __restrict__ item_table,
    const float* __restrict__ rel_table,
    const float* __restrict__ W,
    float* __restrict__ out,      // scores [BATCH]
    float* __restrict__ ws_bce,   // [BATCH]
    float* __restrict__ ws_kge,   // [BATCH]
    float* __restrict__ ws_l2)    // [BATCH]
{
    __shared__ __align__(16) float sRh[N_HOP][N_MEM][DIM];  // 16 KB
    __shared__ __align__(16) float sT[N_HOP][N_MEM][DIM];   // 16 KB
    __shared__ __align__(16) float sH[4][DIM];              // per-wave h staging
    __shared__ __align__(16) float sU[DIM];
    __shared__ __align__(16) float sO[4][DIM];
    __shared__ float sAtt[N_MEM];
    __shared__ float sRedK[4];
    __shared__ float sRedL[4];

    const int b = blockIdx.x;
    const int tid = (int)threadIdx.x;
    const int lane = tid & 63;
    const int w = tid >> 6;

    float kge_acc = 0.f;   // lane-uniform per wave
    float l2_acc = 0.f;    // per-lane

    // ---------------- Phase 1: all (hop,m) pairs ----------------
    for (int p = 0; p < 16; ++p) {
        const int pr = p * 4 + w;            // 0..63, disjoint across waves
        const int hop = pr >> 5;
        const int m = pr & 31;
        const int idx = hop * (BATCH * N_MEM) + b * N_MEM + m;
        const int hidx = mh[idx];            // uniform -> s_load
        const int ridx = mr[idx];
        const int tidx = mt[idx];

        const float hv = item_table[hidx * DIM + lane];  // coalesced 256B row
        const float tv = item_table[tidx * DIM + lane];
        sH[w][lane] = hv;              // wave-private slice; wave-coherent LDS
        sT[hop][m][lane] = tv;         // pair-private slice

        const float4* __restrict__ Rrow =
            (const float4*)(rel_table + (size_t)ridx * (DIM * DIM) + lane * DIM);
        float rh = 0.f, rt = 0.f, l2r = 0.f;
        #pragma unroll
        for (int k = 0; k < 16; ++k) {
            const float4 r4 = Rrow[k];                              // L2-resident
            const float4 h4 = *(const float4*)&sH[w][k * 4];        // broadcast
            const float4 t4 = *(const float4*)&sT[hop][m][k * 4];   // broadcast
            rh += r4.x * h4.x + r4.y * h4.y + r4.z * h4.z + r4.w * h4.w;
            rt += r4.x * t4.x + r4.y * t4.y + r4.z * t4.z + r4.w * t4.w;
            l2r += r4.x * r4.x + r4.y * r4.y + r4.z * r4.z + r4.w * r4.w;
        }
        sRh[hop][m][lane] = rh;
        const float hrt = wave_reduce_sum(hv * rt);   // h . (R t), uniform
        kge_acc += 1.f / (1.f + expf(-hrt));
        l2_acc += hv * hv + tv * tv + l2r;
    }

    l2_acc = wave_reduce_sum(l2_acc);
    if (lane == 0) { sRedK[w] = kge_acc; sRedL[w] = l2_acc; }
    __syncthreads();

    // ---------------- Phase 2: hop-sequential attention ----------------
    float v_i = item_table[items[b] * DIM + lane];   // replicated per wave
    float y_i = 0.f;

    for (int hop = 0; hop < N_HOP; ++hop) {
        // attention logits for this wave's 8 memory slots
        #pragma unroll
        for (int q = 0; q < 8; ++q) {
            const int m = w * 8 + q;
            const float att = wave_reduce_sum(sRh[hop][m][lane] * v_i);
            if (lane == 0) sAtt[m] = att;
        }
        __syncthreads();

        // redundant softmax per thread (32 broadcast LDS reads)
        float mx = -1e30f;
        #pragma unroll
        for (int m = 0; m < N_MEM; ++m) mx = fmaxf(mx, sAtt[m]);
        float se = 0.f;
        float e_loc[8];
        #pragma unroll
        for (int m = 0; m < N_MEM; ++m) {
            const float e = expf(sAtt[m] - mx);
            se += e;
            if ((m >> 3) == w) e_loc[m & 7] = e;
        }
        const float inv = 1.f / se;

        // o partial over this wave's 8 slots
        float op = 0.f;
        #pragma unroll
        for (int q = 0; q < 8; ++q) {
            const int m = w * 8 + q;
            op += sT[hop][m][lane] * (e_loc[q] * inv);
        }
        sO[w][lane] = op;
        __syncthreads();

        const float o_i = sO[0][lane] + sO[1][lane] + sO[2][lane] + sO[3][lane];
        y_i += o_i;
        const float u_i = v_i + o_i;
        if (w == 0) sU[lane] = u_i;
        __syncthreads();

        // v = W (v + o); W row read is L1-resident (same 16KB for all blocks)
        const float4* __restrict__ Wrow = (const float4*)(W + lane * DIM);
        float acc = 0.f;
        #pragma unroll
        for (int k = 0; k < 16; ++k) {
            const float4 w4 = Wrow[k];
            const float4 u4 = *(const float4*)&sU[k * 4];
            acc += w4.x * u4.x + w4.y * u4.y + w4.z * u4.z + w4.w * u4.w;
        }
        v_i = acc;
        __syncthreads();   // protects sAtt/sO/sU overwrite next hop
    }

    float s = wave_reduce_sum(v_i * y_i);
    s = 1.f / (1.f + expf(-s));
    if (tid == 0) {
        out[b] = s;
        const float lab = labels[b];
        const float logp = fmaxf(logf(s), -100.f);
        const float lognp = fmaxf(logf(1.f - s), -100.f);
        ws_bce[b] = lab * logp + (1.f - lab) * lognp;
        ws_kge[b] = sRedK[0] + sRedK[1] + sRedK[2] + sRedK[3];
        ws_l2[b]  = sRedL[0] + sRedL[1] + sRedL[2] + sRedL[3];
    }
}

__global__ __launch_bounds__(256) void ripple_finalize(
    const float* __restrict__ ws_bce,
    const float* __restrict__ ws_kge,
    const float* __restrict__ ws_l2,
    float* __restrict__ out)
{
    __shared__ float sb[4], sk[4], sl[4];
    const int tid = (int)threadIdx.x;
    float bsum = 0.f, ksum = 0.f, lsum = 0.f;
    for (int i = tid; i < BATCH; i += 256) {
        bsum += ws_bce[i];
        ksum += ws_kge[i];
        lsum += ws_l2[i];
    }
    bsum = wave_reduce_sum(bsum);
    ksum = wave_reduce_sum(ksum);
    lsum = wave_reduce_sum(lsum);
    const int w = tid >> 6;
    if ((tid & 63) == 0) { sb[w] = bsum; sk[w] = ksum; sl[w] = lsum; }
    __syncthreads();
    if (tid == 0) {
        const float bs = sb[0] + sb[1] + sb[2] + sb[3];
        const float ks = sk[0] + sk[1] + sk[2] + sk[3];
        const float ls = sl[0] + sl[1] + sl[2] + sl[3];
        const float base_loss = -bs / (float)BATCH;
        const float kge_loss = -0.01f * (ks / (float)(BATCH * N_MEM));
        const float l2_loss = 1e-7f * ls;
        out[BATCH + 0] = base_loss + kge_loss + l2_loss;
        out[BATCH + 1] = base_loss;
        out[BATCH + 2] = kge_loss;
        out[BATCH + 3] = l2_loss;
    }
}

extern "C" void kernel_launch(void* const* d_in, const int* in_sizes, int n_in,
                              void* d_out, int out_size, void* d_ws, size_t ws_size,
                              hipStream_t stream) {
    const int* items        = (const int*)d_in[0];
    const float* labels     = (const float*)d_in[1];
    const int* mh           = (const int*)d_in[2];
    const int* mr           = (const int*)d_in[3];
    const int* mt           = (const int*)d_in[4];
    const float* item_table = (const float*)d_in[5];
    const float* rel_table  = (const float*)d_in[6];
    const float* W          = (const float*)d_in[7];
    float* out = (float*)d_out;

    float* ws = (float*)d_ws;
    float* ws_bce = ws;
    float* ws_kge = ws + BATCH;
    float* ws_l2  = ws + 2 * BATCH;

    ripple_main<<<BATCH, 256, 0, stream>>>(items, labels, mh, mr, mt,
                                           item_table, rel_table, W,
                                           out, ws_bce, ws_kge, ws_l2);
    ripple_finalize<<<1, 256, 0, stream>>>(ws_bce, ws_kge, ws_l2, out);
}

// Round 2
// 187.419 us; speedup vs baseline: 1.2783x; 1.2783x over previous
//
#include <hip/hip_runtime.h>
#include <math.h>

#define N_ENTITY 200000
#define N_REL 32
#define DIM 64
#define N_HOP 2
#define N_MEM 32
#define BATCH 1024
#define PAIR_PER_HOP (BATCH * N_MEM)       // 32768
#define N_PAIR (N_HOP * PAIR_PER_HOP)      // 65536
#define CHUNKS 128
#define PPC (N_PAIR / CHUNKS)              // 512 pairs per chunk
#define NBLK_PAIRS (CHUNKS * N_REL)        // 4096 blocks in pairs kernel

__device__ __forceinline__ float wave_reduce_sum(float v) {
    v += __shfl_xor(v, 1);
    v += __shfl_xor(v, 2);
    v += __shfl_xor(v, 4);
    v += __shfl_xor(v, 8);
    v += __shfl_xor(v, 16);
    v += __shfl_xor(v, 32);
    return v;
}

__device__ __forceinline__ float sigmoidf_(float x) {
    return 1.f / (1.f + expf(-x));
}

// ---------------------------------------------------------------------------
// K1: relation-bucketed pair kernel. One wave per block; block (chunk, r)
// processes pairs p in [chunk*PPC, (chunk+1)*PPC) with mr[p]==r.
// R_r lives in VGPRs (lane i = row i). h/t broadcasts are wave-uniform
// scalar loads -> SGPRs; NO LDS anywhere.
// Outputs: hop0 attention logits (scalar/pair), hop1 Rh vectors (64f/pair),
// per-block KGE and L2 partial sums.
// ---------------------------------------------------------------------------
__global__ __launch_bounds__(64) void ripple_pairs(
    const int* __restrict__ items,
    const int* __restrict__ mh,
    const int* __restrict__ mr,
    const int* __restrict__ mt,
    const float* __restrict__ item_table,
    const float* __restrict__ rel_table,
    float* __restrict__ wsL,      // [PAIR_PER_HOP] hop0 logits
    float* __restrict__ wsRh,     // [PAIR_PER_HOP][DIM] hop1 Rh
    float* __restrict__ ws_kge,   // [NBLK_PAIRS]
    float* __restrict__ ws_l2)    // [NBLK_PAIRS]
{
    const int lane = (int)threadIdx.x;
    const int r = (int)blockIdx.y;
    const int chunk = (int)blockIdx.x;
    const int p0 = chunk * PPC;

    // R row i -> lane i registers (64 VGPR), read once from L2
    float R[DIM];
    const float* __restrict__ Rrow =
        rel_table + (size_t)r * (DIM * DIM) + (size_t)lane * DIM;
    #pragma unroll
    for (int k = 0; k < DIM; k += 4) {
        const float4 q = *(const float4*)(Rrow + k);
        R[k] = q.x; R[k + 1] = q.y; R[k + 2] = q.z; R[k + 3] = q.w;
    }
    // ||R_r||^2 per-lane partial (for analytic count * ||R||^2 L2 term)
    float rsq0 = 0.f, rsq1 = 0.f, rsq2 = 0.f, rsq3 = 0.f;
    #pragma unroll
    for (int k = 0; k < DIM; k += 4) {
        rsq0 = fmaf(R[k], R[k], rsq0);
        rsq1 = fmaf(R[k + 1], R[k + 1], rsq1);
        rsq2 = fmaf(R[k + 2], R[k + 2], rsq2);
        rsq3 = fmaf(R[k + 3], R[k + 3], rsq3);
    }
    const float rsq = (rsq0 + rsq1) + (rsq2 + rsq3);

    float kge = 0.f;    // lane-uniform
    float l2ht = 0.f;   // per-lane
    int cnt = 0;

    for (int g = 0; g < PPC; g += 64) {
        const int pv = p0 + g + lane;
        unsigned long long mask = __ballot(mr[pv] == r);   // coalesced scan
        while (mask) {                                     // uniform loop
            const int bit = __ffsll(mask) - 1;
            mask &= mask - 1;
            const int p = p0 + g + bit;                    // wave-uniform
            ++cnt;
            const int hidx = mh[p];
            const int tidx = mt[p];
            const float* __restrict__ hp = item_table + (size_t)hidx * DIM;
            const float* __restrict__ tp = item_table + (size_t)tidx * DIM;
            const float hl = hp[lane];                     // per-lane (coalesced)
            const float tl = tp[lane];

            float rh0 = 0.f, rh1 = 0.f, rh2 = 0.f, rh3 = 0.f;
            float rt0 = 0.f, rt1 = 0.f, rt2 = 0.f, rt3 = 0.f;
            #pragma unroll
            for (int k = 0; k < DIM; k += 4) {
                const float h0 = hp[k], h1 = hp[k + 1], h2 = hp[k + 2], h3 = hp[k + 3];
                const float t0 = tp[k], t1 = tp[k + 1], t2 = tp[k + 2], t3 = tp[k + 3];
                rh0 = fmaf(R[k], h0, rh0);
                rh1 = fmaf(R[k + 1], h1, rh1);
                rh2 = fmaf(R[k + 2], h2, rh2);
                rh3 = fmaf(R[k + 3], h3, rh3);
                rt0 = fmaf(R[k], t0, rt0);
                rt1 = fmaf(R[k + 1], t1, rt1);
                rt2 = fmaf(R[k + 2], t2, rt2);
                rt3 = fmaf(R[k + 3], t3, rt3);
            }
            const float rhv = (rh0 + rh1) + (rh2 + rh3);   // (R h)_lane
            const float rtv = (rt0 + rt1) + (rt2 + rt3);   // (R t)_lane

            const float hrt = wave_reduce_sum(hl * rtv);   // h . (R t)
            kge += sigmoidf_(hrt);
            l2ht += hl * hl + tl * tl;

            if (p < PAIR_PER_HOP) {
                // hop 0: v0 is known -> finish the logit here, no Rh store
                const int b = p >> 5;   // p = b*32 + m
                const float v0 = item_table[(size_t)items[b] * DIM + lane];
                const float lg = wave_reduce_sum(rhv * v0);
                if (lane == 0) wsL[p] = lg;
            } else {
                wsRh[(size_t)(p - PAIR_PER_HOP) * DIM + lane] = rhv;
            }
        }
    }

    const float l2tot = wave_reduce_sum(fmaf((float)cnt, rsq, l2ht));
    if (lane == 0) {
        const int bid = r * CHUNKS + chunk;
        ws_kge[bid] = kge;
        ws_l2[bid] = l2tot;
    }
}

// ---------------------------------------------------------------------------
// K2: per-batch attention chain. hop0 logits precomputed; hop1 logits from
// wsRh . v1. Softmax -> o -> v = W(v+o) -> score + BCE partial.
// ---------------------------------------------------------------------------
__global__ __launch_bounds__(256) void ripple_attn(
    const int* __restrict__ items,
    const float* __restrict__ labels,
    const int* __restrict__ mt,
    const float* __restrict__ item_table,
    const float* __restrict__ W,
    const float* __restrict__ wsL,
    const float* __restrict__ wsRh,
    float* __restrict__ out,
    float* __restrict__ ws_bce)
{
    __shared__ float sAtt[N_MEM];
    __shared__ __align__(16) float sO[4][DIM];
    __shared__ __align__(16) float sU[DIM];

    const int b = (int)blockIdx.x;
    const int tid = (int)threadIdx.x;
    const int lane = tid & 63;
    const int w = tid >> 6;

    float v_i = item_table[(size_t)items[b] * DIM + lane];
    float y_i = 0.f;

    for (int hop = 0; hop < N_HOP; ++hop) {
        if (hop == 0) {
            if (tid < N_MEM) sAtt[tid] = wsL[b * N_MEM + tid];
        } else {
            #pragma unroll
            for (int q = 0; q < 8; ++q) {
                const int m = w * 8 + q;
                const float rh = wsRh[(size_t)(b * N_MEM + m) * DIM + lane];
                const float att = wave_reduce_sum(rh * v_i);
                if (lane == 0) sAtt[m] = att;
            }
        }
        __syncthreads();

        // redundant softmax per thread over 32 broadcast LDS reads
        float mx = -1e30f;
        #pragma unroll
        for (int m = 0; m < N_MEM; ++m) mx = fmaxf(mx, sAtt[m]);
        float se = 0.f;
        float e_loc[8];
        #pragma unroll
        for (int m = 0; m < N_MEM; ++m) {
            const float e = expf(sAtt[m] - mx);
            se += e;
            if ((m >> 3) == w) e_loc[m & 7] = e;
        }
        const float inv = 1.f / se;

        // o partial over this wave's 8 memory slots (t gathered fresh)
        float op = 0.f;
        #pragma unroll
        for (int q = 0; q < 8; ++q) {
            const int m = w * 8 + q;
            const int tidx = mt[hop * PAIR_PER_HOP + b * N_MEM + m];
            op = fmaf(item_table[(size_t)tidx * DIM + lane], e_loc[q] * inv, op);
        }
        sO[w][lane] = op;
        __syncthreads();

        const float o_i = sO[0][lane] + sO[1][lane] + sO[2][lane] + sO[3][lane];
        y_i += o_i;
        if (w == 0) sU[lane] = v_i + o_i;
        __syncthreads();

        // v = W (v + o); W is L1-resident
        const float4* __restrict__ Wrow = (const float4*)(W + (size_t)lane * DIM);
        float a0 = 0.f, a1 = 0.f, a2 = 0.f, a3 = 0.f;
        #pragma unroll
        for (int k = 0; k < 16; ++k) {
            const float4 w4 = Wrow[k];
            const float4 u4 = *(const float4*)&sU[k * 4];
            a0 = fmaf(w4.x, u4.x, a0);
            a1 = fmaf(w4.y, u4.y, a1);
            a2 = fmaf(w4.z, u4.z, a2);
            a3 = fmaf(w4.w, u4.w, a3);
        }
        v_i = (a0 + a1) + (a2 + a3);
        __syncthreads();   // protect sAtt/sO/sU before next hop
    }

    float s = wave_reduce_sum(v_i * y_i);
    s = 1.f / (1.f + expf(-s));
    if (tid == 0) {
        out[b] = s;
        const float lab = labels[b];
        const float logp = fmaxf(logf(s), -100.f);
        const float lognp = fmaxf(logf(1.f - s), -100.f);
        ws_bce[b] = lab * logp + (1.f - lab) * lognp;
    }
}

// ---------------------------------------------------------------------------
// K3: loss finalize.
// ---------------------------------------------------------------------------
__global__ __launch_bounds__(256) void ripple_finalize(
    const float* __restrict__ ws_bce,
    const float* __restrict__ ws_kge,
    const float* __restrict__ ws_l2,
    float* __restrict__ out)
{
    __shared__ float sb[4], sk[4], sl[4];
    const int tid = (int)threadIdx.x;
    float bsum = 0.f, ksum = 0.f, lsum = 0.f;
    for (int i = tid; i < BATCH; i += 256) bsum += ws_bce[i];
    for (int i = tid; i < NBLK_PAIRS; i += 256) {
        ksum += ws_kge[i];
        lsum += ws_l2[i];
    }
    bsum = wave_reduce_sum(bsum);
    ksum = wave_reduce_sum(ksum);
    lsum = wave_reduce_sum(lsum);
    const int w = tid >> 6;
    if ((tid & 63) == 0) { sb[w] = bsum; sk[w] = ksum; sl[w] = lsum; }
    __syncthreads();
    if (tid == 0) {
        const float bs = sb[0] + sb[1] + sb[2] + sb[3];
        const float ks = sk[0] + sk[1] + sk[2] + sk[3];
        const float ls = sl[0] + sl[1] + sl[2] + sl[3];
        const float base_loss = -bs / (float)BATCH;
        const float kge_loss = -0.01f * (ks / (float)(BATCH * N_MEM));
        const float l2_loss = 1e-7f * ls;
        out[BATCH + 0] = base_loss + kge_loss + l2_loss;
        out[BATCH + 1] = base_loss;
        out[BATCH + 2] = kge_loss;
        out[BATCH + 3] = l2_loss;
    }
}

extern "C" void kernel_launch(void* const* d_in, const int* in_sizes, int n_in,
                              void* d_out, int out_size, void* d_ws, size_t ws_size,
                              hipStream_t stream) {
    const int* items        = (const int*)d_in[0];
    const float* labels     = (const float*)d_in[1];
    const int* mh           = (const int*)d_in[2];
    const int* mr           = (const int*)d_in[3];
    const int* mt           = (const int*)d_in[4];
    const float* item_table = (const float*)d_in[5];
    const float* rel_table  = (const float*)d_in[6];
    const float* W          = (const float*)d_in[7];
    float* out = (float*)d_out;

    // workspace layout (floats):
    //   wsL    [32768]            hop0 logits
    //   wsRh   [32768*64]         hop1 Rh vectors (8.4 MB)
    //   ws_bce [1024]
    //   ws_kge [4096]
    //   ws_l2  [4096]
    float* ws = (float*)d_ws;
    float* wsL    = ws;
    float* wsRh   = ws + PAIR_PER_HOP;
    float* ws_bce = wsRh + (size_t)PAIR_PER_HOP * DIM;
    float* ws_kge = ws_bce + BATCH;
    float* ws_l2  = ws_kge + NBLK_PAIRS;

    dim3 gpairs(CHUNKS, N_REL);
    ripple_pairs<<<gpairs, 64, 0, stream>>>(items, mh, mr, mt,
                                            item_table, rel_table,
                                            wsL, wsRh, ws_kge, ws_l2);
    ripple_attn<<<BATCH, 256, 0, stream>>>(items, labels, mt, item_table, W,
                                           wsL, wsRh, out, ws_bce);
    ripple_finalize<<<1, 256, 0, stream>>>(ws_bce, ws_kge, ws_l2, out);
}